// Round 1
// baseline (1202.211 us; speedup 1.0000x reference)
//
#include <hip/hip_runtime.h>

#define N_ATOMS 4096
#define D_DESC 352

__device__ __forceinline__ float wrap1(float d, float box) {
    return d - box * rintf(d / box);
}

__global__ __launch_bounds__(256) void build_lists_kernel(
    const int* __restrict__ types, int* __restrict__ cnt, int* __restrict__ lists)
{
    int i = blockIdx.x * 256 + threadIdx.x;
    if (i < N_ATOMS) {
        int t = types[i];
        int p = atomicAdd(&cnt[t], 1);
        lists[t * N_ATOMS + p] = i;
    }
}

// One block (256 threads) per atom. Exact sorted top-128 per type via
// bitonic sort of 64-bit keys (dist2 bits << 32 | neighbor index) in LDS.
__global__ __launch_bounds__(256) void descriptor_kernel(
    const float* __restrict__ xyz, const float* __restrict__ box,
    const int* __restrict__ cnt, const int* __restrict__ lists,
    float* __restrict__ desc)
{
    __shared__ unsigned long long keys[N_ATOMS];
    __shared__ float aX[32][3];
    __shared__ float aD[32];
    __shared__ float lfD[4];
    __shared__ int   lfJ[4];
    __shared__ float Amat[9];

    const int i   = blockIdx.x;
    const int tid = threadIdx.x;
    const float bx = box[0], by = box[1], bz = box[2];
    const float xi = xyz[3*i+0], yi = xyz[3*i+1], zi = xyz[3*i+2];

    for (int t = 0; t < 2; ++t) {
        const int n = cnt[t];
        int P = 256;
        while (P < n) P <<= 1;

        for (int m = tid; m < P; m += 256) {
            unsigned long long key = 0xFFFFFFFFFFFFFFFFull;
            if (m < n) {
                int j = lists[t * N_ATOMS + m];
                if (j != i) {
                    float dx = wrap1(xi - xyz[3*j+0], bx);
                    float dy = wrap1(yi - xyz[3*j+1], by);
                    float dz = wrap1(zi - xyz[3*j+2], bz);
                    float d2 = dx*dx + dy*dy + dz*dz;
                    key = ((unsigned long long)__float_as_uint(d2) << 32) | (unsigned)j;
                }
            }
            keys[m] = key;
        }
        __syncthreads();

        for (int k = 2; k <= P; k <<= 1) {
            for (int jj = k >> 1; jj > 0; jj >>= 1) {
                for (int m = tid; m < P; m += 256) {
                    int p = m ^ jj;
                    if (p > m) {
                        unsigned long long a = keys[m], b = keys[p];
                        bool asc = ((m & k) == 0);
                        bool doswap = asc ? (a > b) : (a < b);
                        if (doswap) { keys[m] = b; keys[p] = a; }
                    }
                }
                __syncthreads();
            }
        }

        if (tid < 128) {
            unsigned long long key = keys[tid];
            unsigned j = (unsigned)(key & 0xFFFFFFFFu);
            float d2   = __uint_as_float((unsigned)(key >> 32));
            float dist = sqrtf(d2);
            desc[i * D_DESC + t * 128 + tid] = 1.0f / (dist + 1e-16f);
            if (tid < 16) {
                float dx = wrap1(xi - xyz[3*j+0], bx);
                float dy = wrap1(yi - xyz[3*j+1], by);
                float dz = wrap1(zi - xyz[3*j+2], bz);
                aX[t*16+tid][0] = dx;
                aX[t*16+tid][1] = dy;
                aX[t*16+tid][2] = dz;
                aD[t*16+tid] = dist;
            }
            if (tid < 2) {
                lfD[t*2+tid] = dist;
                lfJ[t*2+tid] = (int)j;
            }
        }
        __syncthreads();   // protect keys[] reuse + aX/aD/lfD visibility
    }

    if (tid == 0) {
        // stable merge: pick 2 smallest of [d0_0, d0_1, d1_0, d1_1]
        int i0 = 0; float b0 = lfD[0];
        for (int c = 1; c < 4; ++c) if (lfD[c] < b0) { b0 = lfD[c]; i0 = c; }
        int i1 = -1; float b1v = 3.4e38f;
        for (int c = 0; c < 4; ++c) { if (c == i0) continue; if (lfD[c] < b1v) { b1v = lfD[c]; i1 = c; } }

        int ja = lfJ[i0], jb = lfJ[i1];
        float da = lfD[i0], db = lfD[i1];
        float r0x = wrap1(xi - xyz[3*ja+0], bx) / (da + 1e-16f);
        float r0y = wrap1(yi - xyz[3*ja+1], by) / (da + 1e-16f);
        float r0z = wrap1(zi - xyz[3*ja+2], bz) / (da + 1e-16f);
        float r1x = wrap1(xi - xyz[3*jb+0], bx) / (db + 1e-16f);
        float r1y = wrap1(yi - xyz[3*jb+1], by) / (db + 1e-16f);
        float r1z = wrap1(zi - xyz[3*jb+2], bz) / (db + 1e-16f);
        float dot = r0x*r1x + r0y*r1y + r0z*r1z;
        float v2x = r1x - dot*r0x, v2y = r1y - dot*r0y, v2z = r1z - dot*r0z;
        float n2 = sqrtf(v2x*v2x + v2y*v2y + v2z*v2z);
        v2x /= n2; v2y /= n2; v2z /= n2;
        float v3x = r0y*r1z - r0z*r1y;
        float v3y = r0z*r1x - r0x*r1z;
        float v3z = r0x*r1y - r0y*r1x;
        float n3 = sqrtf(v3x*v3x + v3y*v3y + v3z*v3z);
        v3x /= n3; v3y /= n3; v3z /= n3;
        Amat[0]=r0x; Amat[1]=r0y; Amat[2]=r0z;
        Amat[3]=v2x; Amat[4]=v2y; Amat[5]=v2z;
        Amat[6]=v3x; Amat[7]=v3y; Amat[8]=v3z;
    }
    __syncthreads();

    if (tid < 32) {
        float d  = aD[tid];
        float dn = d + 1e-16f;
        float ax = aX[tid][0] / dn;
        float ay = aX[tid][1] / dn;
        float az = aX[tid][2] / dn;
        float o0 = (Amat[0]*ax + Amat[1]*ay + Amat[2]*az) / dn;
        float o1 = (Amat[3]*ax + Amat[4]*ay + Amat[5]*az) / dn;
        float o2 = (Amat[6]*ax + Amat[7]*ay + Amat[8]*az) / dn;
        int off = i * D_DESC + 256 + 3*tid;
        desc[off+0] = o0;
        desc[off+1] = o1;
        desc[off+2] = o2;
    }
}

// One block per 16 atoms of the SAME type; thread = output neuron.
// Weight element loaded once, reused for 16 atoms (registers acc[16]).
__global__ __launch_bounds__(256) void mlp_kernel(
    const float* __restrict__ desc, const int* __restrict__ cnt, const int* __restrict__ lists,
    const float* __restrict__ w1, const float* __restrict__ b1,
    const float* __restrict__ w2, const float* __restrict__ b2,
    const float* __restrict__ w3, const float* __restrict__ b3,
    const float* __restrict__ w4, const float* __restrict__ b4,
    float* __restrict__ out)
{
    const int t    = blockIdx.y;
    const int n    = cnt[t];
    const int base = blockIdx.x * 16;
    if (base >= n) return;
    const int nv  = min(16, n - base);
    const int tid = threadIdx.x;

    __shared__ float bufD[16 * 352];
    __shared__ float bufH[16 * 256];
    __shared__ float red[256];

    for (int q = 0; q < 16; ++q) {
        if (q < nv) {
            int atom = lists[t * N_ATOMS + base + q];
            for (int d = tid; d < 352; d += 256)
                bufD[q * 352 + d] = desc[atom * 352 + d];
        } else {
            for (int d = tid; d < 352; d += 256) bufD[q * 352 + d] = 0.0f;
        }
    }
    __syncthreads();

    const float* W1 = w1 + (size_t)t * 352 * 256;
    const float* W2 = w2 + (size_t)t * 256 * 256;
    const float* W3 = w3 + (size_t)t * 256 * 256;
    const float* W4 = w4 + (size_t)t * 256;

    float acc[16];

    // Layer 1: bufD(352) -> bufH(256)
    {
        float bias = b1[t * 256 + tid];
        #pragma unroll
        for (int q = 0; q < 16; ++q) acc[q] = bias;
        for (int d = 0; d < 352; ++d) {
            float w = W1[d * 256 + tid];
            #pragma unroll
            for (int q = 0; q < 16; ++q) acc[q] = fmaf(bufD[q * 352 + d], w, acc[q]);
        }
        #pragma unroll
        for (int q = 0; q < 16; ++q) bufH[q * 256 + tid] = tanhf(acc[q]);
    }
    __syncthreads();

    // Layer 2: bufH -> bufD (first 16*256 region)
    {
        float bias = b2[t * 256 + tid];
        #pragma unroll
        for (int q = 0; q < 16; ++q) acc[q] = bias;
        for (int g = 0; g < 256; ++g) {
            float w = W2[g * 256 + tid];
            #pragma unroll
            for (int q = 0; q < 16; ++q) acc[q] = fmaf(bufH[q * 256 + g], w, acc[q]);
        }
        #pragma unroll
        for (int q = 0; q < 16; ++q) bufD[q * 256 + tid] = tanhf(acc[q]);
    }
    __syncthreads();

    // Layer 3: bufD -> bufH
    {
        float bias = b3[t * 256 + tid];
        #pragma unroll
        for (int q = 0; q < 16; ++q) acc[q] = bias;
        for (int g = 0; g < 256; ++g) {
            float w = W3[g * 256 + tid];
            #pragma unroll
            for (int q = 0; q < 16; ++q) acc[q] = fmaf(bufD[q * 256 + g], w, acc[q]);
        }
        #pragma unroll
        for (int q = 0; q < 16; ++q) bufH[q * 256 + tid] = tanhf(acc[q]);
    }
    __syncthreads();

    // Layer 4 + energy sum: e = sum_q (b4 + sum_f h3[q][f] * w4[f])
    float colsum = 0.0f;
    for (int q = 0; q < nv; ++q) colsum += bufH[q * 256 + tid];
    red[tid] = colsum * W4[tid];
    __syncthreads();
    for (int w = 128; w > 0; w >>= 1) {
        if (tid < w) red[tid] += red[tid + w];
        __syncthreads();
    }
    if (tid == 0) atomicAdd(out, red[0] + (float)nv * b4[t]);
}

extern "C" void kernel_launch(void* const* d_in, const int* in_sizes, int n_in,
                              void* d_out, int out_size, void* d_ws, size_t ws_size,
                              hipStream_t stream) {
    const float* xyz   = (const float*)d_in[0];
    const float* box   = (const float*)d_in[1];
    const int*   types = (const int*)  d_in[2];
    const float* w1 = (const float*)d_in[3];
    const float* b1 = (const float*)d_in[4];
    const float* w2 = (const float*)d_in[5];
    const float* b2 = (const float*)d_in[6];
    const float* w3 = (const float*)d_in[7];
    const float* b3 = (const float*)d_in[8];
    const float* w4 = (const float*)d_in[9];
    const float* b4 = (const float*)d_in[10];
    float* out = (float*)d_out;

    int*   cnt   = (int*)d_ws;                       // 2 ints
    int*   lists = (int*)d_ws + 16;                  // 2 * 4096 ints
    float* desc  = (float*)d_ws + 16 + 2 * N_ATOMS;  // 4096 * 352 floats

    hipMemsetAsync(d_out, 0, sizeof(float), stream);
    hipMemsetAsync(d_ws, 0, 2 * sizeof(int), stream);

    build_lists_kernel<<<N_ATOMS / 256, 256, 0, stream>>>(types, cnt, lists);
    descriptor_kernel<<<N_ATOMS, 256, 0, stream>>>(xyz, box, cnt, lists, desc);
    dim3 g(256, 2);
    mlp_kernel<<<g, 256, 0, stream>>>(desc, cnt, lists,
                                      w1, b1, w2, b2, w3, b3, w4, b4, out);
}

// Round 2
// 302.633 us; speedup vs baseline: 3.9725x; 3.9725x over previous
//
#include <hip/hip_runtime.h>

#define N_ATOMS 4096
#define D_DESC 352
typedef unsigned long long ull;

__device__ __forceinline__ float wrap1(float d, float box) {
    return d - box * rintf(d / box);
}

__global__ __launch_bounds__(256) void build_lists_kernel(
    const int* __restrict__ types, int* __restrict__ cnt, int* __restrict__ lists)
{
    int i = blockIdx.x * 256 + threadIdx.x;
    if (i < N_ATOMS) {
        int t = types[i];
        int p = atomicAdd(&cnt[t], 1);
        lists[t * N_ATOMS + p] = i;
    }
}

// One block per (atom, type). Exact sorted top-128 via register-resident
// binary search on 43-bit keys (d2bits<<12 | j), then 128-elem bitonic sort.
__global__ __launch_bounds__(256) void select_kernel(
    const float* __restrict__ xyz, const float* __restrict__ box,
    const int* __restrict__ cnt, const int* __restrict__ lists,
    float* __restrict__ desc, float* __restrict__ aX, float* __restrict__ aD,
    float* __restrict__ lfD, int* __restrict__ lfJ)
{
    __shared__ int   part[2][4];
    __shared__ ull   cand[128];
    __shared__ int   cpos;

    const int i   = blockIdx.x >> 1;
    const int t   = blockIdx.x & 1;
    const int tid = threadIdx.x;
    const int n   = cnt[t];
    const float bx = box[0], by = box[1], bz = box[2];
    const float xi = xyz[3*i+0], yi = xyz[3*i+1], zi = xyz[3*i+2];

    // --- load keys into registers (up to 16 per thread) ---
    ull k[16];
    #pragma unroll
    for (int c = 0; c < 16; ++c) {
        int m = tid + c * 256;
        ull key = ~0ull;
        if (m < n) {
            int j = lists[t * N_ATOMS + m];
            if (j != i) {
                float dx = wrap1(xi - xyz[3*j+0], bx);
                float dy = wrap1(yi - xyz[3*j+1], by);
                float dz = wrap1(zi - xyz[3*j+2], bz);
                float d2 = dx*dx + dy*dy + dz*dz;
                key = ((ull)__float_as_uint(d2) << 12) | (unsigned)j;
            }
        }
        k[c] = key;
    }

    if (tid == 0) cpos = 0;

    // --- greedy MSB-first: max C with count(key < C) <= 128  => C = 129th smallest ---
    ull C = 0;
    int r = 0;
    for (int bit = 42; bit >= 0; --bit, ++r) {
        ull trial = C | (1ull << bit);
        int lc = 0;
        #pragma unroll
        for (int c = 0; c < 16; ++c) lc += (k[c] < trial) ? 1 : 0;
        #pragma unroll
        for (int off = 32; off > 0; off >>= 1) lc += __shfl_xor(lc, off);
        if ((tid & 63) == 0) part[r & 1][tid >> 6] = lc;
        __syncthreads();
        int tot = part[r & 1][0] + part[r & 1][1] + part[r & 1][2] + part[r & 1][3];
        if (tot <= 128) C = trial;
    }

    // --- collect exactly the 128 keys < C ---
    #pragma unroll
    for (int c = 0; c < 16; ++c) {
        if (k[c] < C) { int p = atomicAdd(&cpos, 1); cand[p] = k[c]; }
    }
    __syncthreads();

    // --- bitonic sort of 128 candidates ---
    for (int kk = 2; kk <= 128; kk <<= 1) {
        for (int jj = kk >> 1; jj > 0; jj >>= 1) {
            if (tid < 128) {
                int p = tid ^ jj;
                if (p > tid) {
                    ull a = cand[tid], b = cand[p];
                    bool asc = ((tid & kk) == 0);
                    if (asc ? (a > b) : (a < b)) { cand[tid] = b; cand[p] = a; }
                }
            }
            __syncthreads();
        }
    }

    // --- outputs ---
    if (tid < 128) {
        ull key = cand[tid];
        int j   = (int)(key & 0xFFF);
        float d2 = __uint_as_float((unsigned)(key >> 12));
        float dist = sqrtf(d2);
        desc[i * D_DESC + t * 128 + tid] = 1.0f / (dist + 1e-16f);
        if (tid < 16) {
            float dx = wrap1(xi - xyz[3*j+0], bx);
            float dy = wrap1(yi - xyz[3*j+1], by);
            float dz = wrap1(zi - xyz[3*j+2], bz);
            int s = i * 32 + t * 16 + tid;
            aX[3*s+0] = dx; aX[3*s+1] = dy; aX[3*s+2] = dz;
            aD[s] = dist;
        }
        if (tid < 2) {
            lfD[i * 4 + t * 2 + tid] = dist;
            lfJ[i * 4 + t * 2 + tid] = j;
        }
    }
}

// One block (64 threads) per atom: local frame + rotated angular features.
__global__ __launch_bounds__(64) void finalize_kernel(
    const float* __restrict__ xyz, const float* __restrict__ box,
    const float* __restrict__ aX, const float* __restrict__ aD,
    const float* __restrict__ lfD, const int* __restrict__ lfJ,
    float* __restrict__ desc)
{
    __shared__ float Amat[9];
    const int i   = blockIdx.x;
    const int tid = threadIdx.x;

    if (tid == 0) {
        const float bx = box[0], by = box[1], bz = box[2];
        const float xi = xyz[3*i+0], yi = xyz[3*i+1], zi = xyz[3*i+2];
        float cd[4]; int cj[4];
        #pragma unroll
        for (int c = 0; c < 4; ++c) { cd[c] = lfD[i*4+c]; cj[c] = lfJ[i*4+c]; }
        // stable 2-smallest (argsort stable: first occurrence wins ties)
        int i0 = 0; float b0 = cd[0];
        for (int c = 1; c < 4; ++c) if (cd[c] < b0) { b0 = cd[c]; i0 = c; }
        int i1 = -1; float b1v = 3.4e38f;
        for (int c = 0; c < 4; ++c) { if (c == i0) continue; if (cd[c] < b1v) { b1v = cd[c]; i1 = c; } }

        int ja = cj[i0], jb = cj[i1];
        float da = cd[i0], db = cd[i1];
        float r0x = wrap1(xi - xyz[3*ja+0], bx) / (da + 1e-16f);
        float r0y = wrap1(yi - xyz[3*ja+1], by) / (da + 1e-16f);
        float r0z = wrap1(zi - xyz[3*ja+2], bz) / (da + 1e-16f);
        float r1x = wrap1(xi - xyz[3*jb+0], bx) / (db + 1e-16f);
        float r1y = wrap1(yi - xyz[3*jb+1], by) / (db + 1e-16f);
        float r1z = wrap1(zi - xyz[3*jb+2], bz) / (db + 1e-16f);
        float dot = r0x*r1x + r0y*r1y + r0z*r1z;
        float v2x = r1x - dot*r0x, v2y = r1y - dot*r0y, v2z = r1z - dot*r0z;
        float n2 = sqrtf(v2x*v2x + v2y*v2y + v2z*v2z);
        v2x /= n2; v2y /= n2; v2z /= n2;
        float v3x = r0y*r1z - r0z*r1y;
        float v3y = r0z*r1x - r0x*r1z;
        float v3z = r0x*r1y - r0y*r1x;
        float n3 = sqrtf(v3x*v3x + v3y*v3y + v3z*v3z);
        v3x /= n3; v3y /= n3; v3z /= n3;
        Amat[0]=r0x; Amat[1]=r0y; Amat[2]=r0z;
        Amat[3]=v2x; Amat[4]=v2y; Amat[5]=v2z;
        Amat[6]=v3x; Amat[7]=v3y; Amat[8]=v3z;
    }
    __syncthreads();

    if (tid < 32) {
        int s = i * 32 + tid;
        float d  = aD[s];
        float dn = d + 1e-16f;
        float ax = aX[3*s+0] / dn;
        float ay = aX[3*s+1] / dn;
        float az = aX[3*s+2] / dn;
        float o0 = (Amat[0]*ax + Amat[1]*ay + Amat[2]*az) / dn;
        float o1 = (Amat[3]*ax + Amat[4]*ay + Amat[5]*az) / dn;
        float o2 = (Amat[6]*ax + Amat[7]*ay + Amat[8]*az) / dn;
        int off = i * D_DESC + 256 + 3*tid;
        desc[off+0] = o0;
        desc[off+1] = o1;
        desc[off+2] = o2;
    }
}

// One block per 16 atoms of the SAME type; thread = output neuron.
__global__ __launch_bounds__(256) void mlp_kernel(
    const float* __restrict__ desc, const int* __restrict__ cnt, const int* __restrict__ lists,
    const float* __restrict__ w1, const float* __restrict__ b1,
    const float* __restrict__ w2, const float* __restrict__ b2,
    const float* __restrict__ w3, const float* __restrict__ b3,
    const float* __restrict__ w4, const float* __restrict__ b4,
    float* __restrict__ out)
{
    const int t    = blockIdx.y;
    const int n    = cnt[t];
    const int base = blockIdx.x * 16;
    if (base >= n) return;
    const int nv  = min(16, n - base);
    const int tid = threadIdx.x;

    __shared__ float bufD[16 * 352];
    __shared__ float bufH[16 * 256];
    __shared__ float red[256];

    for (int q = 0; q < 16; ++q) {
        if (q < nv) {
            int atom = lists[t * N_ATOMS + base + q];
            for (int d = tid; d < 352; d += 256)
                bufD[q * 352 + d] = desc[atom * 352 + d];
        } else {
            for (int d = tid; d < 352; d += 256) bufD[q * 352 + d] = 0.0f;
        }
    }
    __syncthreads();

    const float* W1 = w1 + (size_t)t * 352 * 256;
    const float* W2 = w2 + (size_t)t * 256 * 256;
    const float* W3 = w3 + (size_t)t * 256 * 256;
    const float* W4 = w4 + (size_t)t * 256;

    float acc[16];

    {
        float bias = b1[t * 256 + tid];
        #pragma unroll
        for (int q = 0; q < 16; ++q) acc[q] = bias;
        for (int d = 0; d < 352; ++d) {
            float w = W1[d * 256 + tid];
            #pragma unroll
            for (int q = 0; q < 16; ++q) acc[q] = fmaf(bufD[q * 352 + d], w, acc[q]);
        }
        #pragma unroll
        for (int q = 0; q < 16; ++q) bufH[q * 256 + tid] = tanhf(acc[q]);
    }
    __syncthreads();

    {
        float bias = b2[t * 256 + tid];
        #pragma unroll
        for (int q = 0; q < 16; ++q) acc[q] = bias;
        for (int g = 0; g < 256; ++g) {
            float w = W2[g * 256 + tid];
            #pragma unroll
            for (int q = 0; q < 16; ++q) acc[q] = fmaf(bufH[q * 256 + g], w, acc[q]);
        }
        #pragma unroll
        for (int q = 0; q < 16; ++q) bufD[q * 256 + tid] = tanhf(acc[q]);
    }
    __syncthreads();

    {
        float bias = b3[t * 256 + tid];
        #pragma unroll
        for (int q = 0; q < 16; ++q) acc[q] = bias;
        for (int g = 0; g < 256; ++g) {
            float w = W3[g * 256 + tid];
            #pragma unroll
            for (int q = 0; q < 16; ++q) acc[q] = fmaf(bufD[q * 256 + g], w, acc[q]);
        }
        #pragma unroll
        for (int q = 0; q < 16; ++q) bufH[q * 256 + tid] = tanhf(acc[q]);
    }
    __syncthreads();

    float colsum = 0.0f;
    for (int q = 0; q < nv; ++q) colsum += bufH[q * 256 + tid];
    red[tid] = colsum * W4[tid];
    __syncthreads();
    for (int w = 128; w > 0; w >>= 1) {
        if (tid < w) red[tid] += red[tid + w];
        __syncthreads();
    }
    if (tid == 0) atomicAdd(out, red[0] + (float)nv * b4[t]);
}

extern "C" void kernel_launch(void* const* d_in, const int* in_sizes, int n_in,
                              void* d_out, int out_size, void* d_ws, size_t ws_size,
                              hipStream_t stream) {
    const float* xyz   = (const float*)d_in[0];
    const float* box   = (const float*)d_in[1];
    const int*   types = (const int*)  d_in[2];
    const float* w1 = (const float*)d_in[3];
    const float* b1 = (const float*)d_in[4];
    const float* w2 = (const float*)d_in[5];
    const float* b2 = (const float*)d_in[6];
    const float* w3 = (const float*)d_in[7];
    const float* b3 = (const float*)d_in[8];
    const float* w4 = (const float*)d_in[9];
    const float* b4 = (const float*)d_in[10];
    float* out = (float*)d_out;

    // workspace layout (floats/ints, 4B units)
    int*   cnt   = (int*)d_ws;                               // 16 ints reserved
    int*   lists = (int*)d_ws + 16;                          // 2*4096
    float* desc  = (float*)d_ws + 16 + 2 * N_ATOMS;          // 4096*352
    float* aX    = desc + (size_t)N_ATOMS * D_DESC;          // 4096*32*3
    float* aD    = aX + (size_t)N_ATOMS * 96;                // 4096*32
    float* lfD   = aD + (size_t)N_ATOMS * 32;                // 4096*4
    int*   lfJ   = (int*)(lfD + (size_t)N_ATOMS * 4);        // 4096*4

    hipMemsetAsync(d_out, 0, sizeof(float), stream);
    hipMemsetAsync(d_ws, 0, 2 * sizeof(int), stream);

    build_lists_kernel<<<N_ATOMS / 256, 256, 0, stream>>>(types, cnt, lists);
    select_kernel<<<2 * N_ATOMS, 256, 0, stream>>>(xyz, box, cnt, lists,
                                                   desc, aX, aD, lfD, lfJ);
    finalize_kernel<<<N_ATOMS, 64, 0, stream>>>(xyz, box, aX, aD, lfD, lfJ, desc);
    dim3 g(256, 2);
    mlp_kernel<<<g, 256, 0, stream>>>(desc, cnt, lists,
                                      w1, b1, w2, b2, w3, b3, w4, b4, out);
}

// Round 3
// 226.177 us; speedup vs baseline: 5.3153x; 1.3380x over previous
//
#include <hip/hip_runtime.h>

#define N_ATOMS 4096
#define D_DESC 352
typedef unsigned long long ull;

__device__ __forceinline__ float wrap1(float d, float box) {
    return d - box * rintf(d / box);
}

__global__ __launch_bounds__(256) void build_lists_kernel(
    const int* __restrict__ types, int* __restrict__ cnt, int* __restrict__ lists)
{
    int i = blockIdx.x * 256 + threadIdx.x;
    if (i < N_ATOMS) {
        int t = types[i];
        int p = atomicAdd(&cnt[t], 1);
        lists[t * N_ATOMS + p] = i;
    }
}

// One block per (atom, type). Threshold-filter to <=512 candidates
// (analytic initial radius + multiplicative adjust), then exact bitonic
// sort of candidates by 43-bit key (d2bits<<12 | j) -> sorted top-128.
__global__ __launch_bounds__(256) void select_kernel(
    const float* __restrict__ xyz, const float* __restrict__ box,
    const int* __restrict__ cnt, const int* __restrict__ lists,
    float* __restrict__ desc, float* __restrict__ aX, float* __restrict__ aD,
    float* __restrict__ lfD, int* __restrict__ lfJ)
{
    __shared__ int part[2][4];
    __shared__ ull cand[512];
    __shared__ int cpos;

    const int i   = blockIdx.x >> 1;
    const int t   = blockIdx.x & 1;
    const int tid = threadIdx.x;
    const int n   = cnt[t];
    const int nc  = (n + 255) >> 8;          // keys per thread actually used
    const float bx = box[0], by = box[1], bz = box[2];
    const float xi = xyz[3*i+0], yi = xyz[3*i+1], zi = xyz[3*i+2];

    // --- distances into registers (d2 only; j re-gathered on collect) ---
    float d2r[16];
    #pragma unroll
    for (int c = 0; c < 16; ++c) {
        d2r[c] = __builtin_inff();
        if (c < nc) {
            int m = tid + (c << 8);
            if (m < n) {
                int j = lists[t * N_ATOMS + m];
                if (j != i) {
                    float dx = wrap1(xi - xyz[3*j+0], bx);
                    float dy = wrap1(yi - xyz[3*j+1], by);
                    float dz = wrap1(zi - xyz[3*j+2], bz);
                    d2r[c] = dx*dx + dy*dy + dz*dz;
                }
            }
        }
    }

    if (tid == 0) cpos = 0;

    // --- find T with count(d2 < T) in [128, 384]; analytic start ~192 nbrs ---
    float T = __powf(45.84f * bx * by * bz / (float)n, 2.0f / 3.0f);
    int tot = 0;
    for (int it = 0; it < 20; ++it) {
        int lc = 0;
        #pragma unroll
        for (int c = 0; c < 16; ++c)
            if (c < nc) lc += (d2r[c] < T) ? 1 : 0;
        #pragma unroll
        for (int off = 32; off > 0; off >>= 1) lc += __shfl_xor(lc, off);
        if ((tid & 63) == 0) part[it & 1][tid >> 6] = lc;
        __syncthreads();
        tot = part[it & 1][0] + part[it & 1][1] + part[it & 1][2] + part[it & 1][3];
        if (tot >= 128 && tot <= 384) break;
        T *= (tot < 128) ? 1.6f : 0.6f;
    }

    // --- collect all keys below T (>=128 of them => contains exact top-128) ---
    #pragma unroll
    for (int c = 0; c < 16; ++c) {
        if (c < nc && d2r[c] < T) {
            int m = tid + (c << 8);
            int j = lists[t * N_ATOMS + m];
            ull key = ((ull)__float_as_uint(d2r[c]) << 12) | (unsigned)j;
            int p = atomicAdd(&cpos, 1);
            if (p < 512) cand[p] = key;
        }
    }
    const int count   = (tot <= 512) ? tot : 512;
    const int sort_n  = (count <= 256) ? 256 : 512;
    for (int m = tid + count; m < sort_n; m += 256) cand[m] = ~0ull;
    __syncthreads();

    // --- bitonic sort of sort_n candidates ---
    for (int kk = 2; kk <= sort_n; kk <<= 1) {
        for (int jj = kk >> 1; jj > 0; jj >>= 1) {
            for (int m = tid; m < sort_n; m += 256) {
                int p = m ^ jj;
                if (p > m) {
                    ull a = cand[m], b = cand[p];
                    bool asc = ((m & kk) == 0);
                    if (asc ? (a > b) : (a < b)) { cand[m] = b; cand[p] = a; }
                }
            }
            __syncthreads();
        }
    }

    // --- outputs ---
    if (tid < 128) {
        ull key = cand[tid];
        int j   = (int)(key & 0xFFF);
        float d2 = __uint_as_float((unsigned)(key >> 12));
        float dist = sqrtf(d2);
        desc[i * D_DESC + t * 128 + tid] = 1.0f / (dist + 1e-16f);
        if (tid < 16) {
            float dx = wrap1(xi - xyz[3*j+0], bx);
            float dy = wrap1(yi - xyz[3*j+1], by);
            float dz = wrap1(zi - xyz[3*j+2], bz);
            int s = i * 32 + t * 16 + tid;
            aX[3*s+0] = dx; aX[3*s+1] = dy; aX[3*s+2] = dz;
            aD[s] = dist;
        }
        if (tid < 2) {
            lfD[i * 4 + t * 2 + tid] = dist;
            lfJ[i * 4 + t * 2 + tid] = j;
        }
    }
}

// One block (64 threads) per atom: local frame + rotated angular features.
__global__ __launch_bounds__(64) void finalize_kernel(
    const float* __restrict__ xyz, const float* __restrict__ box,
    const float* __restrict__ aX, const float* __restrict__ aD,
    const float* __restrict__ lfD, const int* __restrict__ lfJ,
    float* __restrict__ desc)
{
    __shared__ float Amat[9];
    const int i   = blockIdx.x;
    const int tid = threadIdx.x;

    if (tid == 0) {
        const float bx = box[0], by = box[1], bz = box[2];
        const float xi = xyz[3*i+0], yi = xyz[3*i+1], zi = xyz[3*i+2];
        float cd[4]; int cj[4];
        #pragma unroll
        for (int c = 0; c < 4; ++c) { cd[c] = lfD[i*4+c]; cj[c] = lfJ[i*4+c]; }
        int i0 = 0; float b0 = cd[0];
        for (int c = 1; c < 4; ++c) if (cd[c] < b0) { b0 = cd[c]; i0 = c; }
        int i1 = -1; float b1v = 3.4e38f;
        for (int c = 0; c < 4; ++c) { if (c == i0) continue; if (cd[c] < b1v) { b1v = cd[c]; i1 = c; } }

        int ja = cj[i0], jb = cj[i1];
        float da = cd[i0], db = cd[i1];
        float r0x = wrap1(xi - xyz[3*ja+0], bx) / (da + 1e-16f);
        float r0y = wrap1(yi - xyz[3*ja+1], by) / (da + 1e-16f);
        float r0z = wrap1(zi - xyz[3*ja+2], bz) / (da + 1e-16f);
        float r1x = wrap1(xi - xyz[3*jb+0], bx) / (db + 1e-16f);
        float r1y = wrap1(yi - xyz[3*jb+1], by) / (db + 1e-16f);
        float r1z = wrap1(zi - xyz[3*jb+2], bz) / (db + 1e-16f);
        float dot = r0x*r1x + r0y*r1y + r0z*r1z;
        float v2x = r1x - dot*r0x, v2y = r1y - dot*r0y, v2z = r1z - dot*r0z;
        float n2 = sqrtf(v2x*v2x + v2y*v2y + v2z*v2z);
        v2x /= n2; v2y /= n2; v2z /= n2;
        float v3x = r0y*r1z - r0z*r1y;
        float v3y = r0z*r1x - r0x*r1z;
        float v3z = r0x*r1y - r0y*r1x;
        float n3 = sqrtf(v3x*v3x + v3y*v3y + v3z*v3z);
        v3x /= n3; v3y /= n3; v3z /= n3;
        Amat[0]=r0x; Amat[1]=r0y; Amat[2]=r0z;
        Amat[3]=v2x; Amat[4]=v2y; Amat[5]=v2z;
        Amat[6]=v3x; Amat[7]=v3y; Amat[8]=v3z;
    }
    __syncthreads();

    if (tid < 32) {
        int s = i * 32 + tid;
        float d  = aD[s];
        float dn = d + 1e-16f;
        float ax = aX[3*s+0] / dn;
        float ay = aX[3*s+1] / dn;
        float az = aX[3*s+2] / dn;
        float o0 = (Amat[0]*ax + Amat[1]*ay + Amat[2]*az) / dn;
        float o1 = (Amat[3]*ax + Amat[4]*ay + Amat[5]*az) / dn;
        float o2 = (Amat[6]*ax + Amat[7]*ay + Amat[8]*az) / dn;
        int off = i * D_DESC + 256 + 3*tid;
        desc[off+0] = o0;
        desc[off+1] = o1;
        desc[off+2] = o2;
    }
}

// One block per 16 atoms of the SAME type; thread = output neuron.
__global__ __launch_bounds__(256) void mlp_kernel(
    const float* __restrict__ desc, const int* __restrict__ cnt, const int* __restrict__ lists,
    const float* __restrict__ w1, const float* __restrict__ b1,
    const float* __restrict__ w2, const float* __restrict__ b2,
    const float* __restrict__ w3, const float* __restrict__ b3,
    const float* __restrict__ w4, const float* __restrict__ b4,
    float* __restrict__ out)
{
    const int t    = blockIdx.y;
    const int n    = cnt[t];
    const int base = blockIdx.x * 16;
    if (base >= n) return;
    const int nv  = min(16, n - base);
    const int tid = threadIdx.x;

    __shared__ float bufD[16 * 352];
    __shared__ float bufH[16 * 256];
    __shared__ float red[256];

    for (int q = 0; q < 16; ++q) {
        if (q < nv) {
            int atom = lists[t * N_ATOMS + base + q];
            for (int d = tid; d < 352; d += 256)
                bufD[q * 352 + d] = desc[atom * 352 + d];
        } else {
            for (int d = tid; d < 352; d += 256) bufD[q * 352 + d] = 0.0f;
        }
    }
    __syncthreads();

    const float* W1 = w1 + (size_t)t * 352 * 256;
    const float* W2 = w2 + (size_t)t * 256 * 256;
    const float* W3 = w3 + (size_t)t * 256 * 256;
    const float* W4 = w4 + (size_t)t * 256;

    float acc[16];

    {
        float bias = b1[t * 256 + tid];
        #pragma unroll
        for (int q = 0; q < 16; ++q) acc[q] = bias;
        for (int d = 0; d < 352; ++d) {
            float w = W1[d * 256 + tid];
            #pragma unroll
            for (int q = 0; q < 16; ++q) acc[q] = fmaf(bufD[q * 352 + d], w, acc[q]);
        }
        #pragma unroll
        for (int q = 0; q < 16; ++q) bufH[q * 256 + tid] = tanhf(acc[q]);
    }
    __syncthreads();

    {
        float bias = b2[t * 256 + tid];
        #pragma unroll
        for (int q = 0; q < 16; ++q) acc[q] = bias;
        for (int g = 0; g < 256; ++g) {
            float w = W2[g * 256 + tid];
            #pragma unroll
            for (int q = 0; q < 16; ++q) acc[q] = fmaf(bufH[q * 256 + g], w, acc[q]);
        }
        #pragma unroll
        for (int q = 0; q < 16; ++q) bufD[q * 256 + tid] = tanhf(acc[q]);
    }
    __syncthreads();

    {
        float bias = b3[t * 256 + tid];
        #pragma unroll
        for (int q = 0; q < 16; ++q) acc[q] = bias;
        for (int g = 0; g < 256; ++g) {
            float w = W3[g * 256 + tid];
            #pragma unroll
            for (int q = 0; q < 16; ++q) acc[q] = fmaf(bufD[q * 256 + g], w, acc[q]);
        }
        #pragma unroll
        for (int q = 0; q < 16; ++q) bufH[q * 256 + tid] = tanhf(acc[q]);
    }
    __syncthreads();

    float colsum = 0.0f;
    for (int q = 0; q < nv; ++q) colsum += bufH[q * 256 + tid];
    red[tid] = colsum * W4[tid];
    __syncthreads();
    for (int w = 128; w > 0; w >>= 1) {
        if (tid < w) red[tid] += red[tid + w];
        __syncthreads();
    }
    if (tid == 0) atomicAdd(out, red[0] + (float)nv * b4[t]);
}

extern "C" void kernel_launch(void* const* d_in, const int* in_sizes, int n_in,
                              void* d_out, int out_size, void* d_ws, size_t ws_size,
                              hipStream_t stream) {
    const float* xyz   = (const float*)d_in[0];
    const float* box   = (const float*)d_in[1];
    const int*   types = (const int*)  d_in[2];
    const float* w1 = (const float*)d_in[3];
    const float* b1 = (const float*)d_in[4];
    const float* w2 = (const float*)d_in[5];
    const float* b2 = (const float*)d_in[6];
    const float* w3 = (const float*)d_in[7];
    const float* b3 = (const float*)d_in[8];
    const float* w4 = (const float*)d_in[9];
    const float* b4 = (const float*)d_in[10];
    float* out = (float*)d_out;

    int*   cnt   = (int*)d_ws;                               // 16 ints reserved
    int*   lists = (int*)d_ws + 16;                          // 2*4096
    float* desc  = (float*)d_ws + 16 + 2 * N_ATOMS;          // 4096*352
    float* aX    = desc + (size_t)N_ATOMS * D_DESC;          // 4096*32*3
    float* aD    = aX + (size_t)N_ATOMS * 96;                // 4096*32
    float* lfD   = aD + (size_t)N_ATOMS * 32;                // 4096*4
    int*   lfJ   = (int*)(lfD + (size_t)N_ATOMS * 4);        // 4096*4

    hipMemsetAsync(d_out, 0, sizeof(float), stream);
    hipMemsetAsync(d_ws, 0, 2 * sizeof(int), stream);

    build_lists_kernel<<<N_ATOMS / 256, 256, 0, stream>>>(types, cnt, lists);
    select_kernel<<<2 * N_ATOMS, 256, 0, stream>>>(xyz, box, cnt, lists,
                                                   desc, aX, aD, lfD, lfJ);
    finalize_kernel<<<N_ATOMS, 64, 0, stream>>>(xyz, box, aX, aD, lfD, lfJ, desc);
    dim3 g(256, 2);
    mlp_kernel<<<g, 256, 0, stream>>>(desc, cnt, lists,
                                      w1, b1, w2, b2, w3, b3, w4, b4, out);
}